// Round 1
// baseline (797.698 us; speedup 1.0000x reference)
//
#include <hip/hip_runtime.h>
#include <math.h>

constexpr int BB  = 32;
constexpr int SQL = 2048;
constexpr int SKL = 2048;
constexpr int DD  = 64;
constexpr int TQ  = 16;            // q rows per block
constexpr int TK  = 64;            // k cols per chunk
constexpr int NCK = SKL / TK;      // 32 chunks

__global__ __launch_bounds__(256) void sdpa_fwd(
    const float* __restrict__ q,
    const float* __restrict__ k,
    const int*   __restrict__ mask,
    float*       __restrict__ out)
{
    __shared__ float s_q[TQ][DD];          // q tile, pre-scaled by 1/8
    __shared__ float s_kT[DD][TK + 1];     // transposed k chunk, +1 pad

    const int t  = threadIdx.x;
    const int tx = t & 63;                 // lane = column within chunk
    const int ty = t >> 6;                 // wave id 0..3
    const int b  = blockIdx.y;
    const int r0 = blockIdx.x * TQ;

    // ---- stage q tile (scaled). 256 threads x 1 float4 = 16x64
    {
        const int row = t >> 4;            // 0..15
        const int d0  = (t & 15) << 2;     // 0,4,...,60
        float4 v = *reinterpret_cast<const float4*>(
            q + ((size_t)b * SQL + (size_t)(r0 + row)) * DD + d0);
        v.x *= 0.125f; v.y *= 0.125f; v.z *= 0.125f; v.w *= 0.125f;
        *reinterpret_cast<float4*>(&s_q[row][d0]) = v;
    }

    float sc[4][NCK];                      // register-resident scores
    float pmax[4] = {-INFINITY, -INFINITY, -INFINITY, -INFINITY};

    const float* kb = k + (size_t)b * SKL * DD;
    const int*   mb = mask + ((size_t)b * SQL + (size_t)r0) * SKL + tx;

    #pragma unroll
    for (int ck = 0; ck < NCK; ++ck) {
        __syncthreads();                   // protect s_kT (and first-iter q)
        // ---- stage k chunk, transposed into LDS
        #pragma unroll
        for (int i = 0; i < 4; ++i) {
            const int idx = t + 256 * i;   // 0..1023 float4 id over 64x64 tile
            const int row = idx >> 4;      // 0..63 (k row within chunk)
            const int d0  = (idx & 15) << 2;
            const float4 v = *reinterpret_cast<const float4*>(
                kb + (size_t)(ck * TK + row) * DD + d0);
            s_kT[d0 + 0][row] = v.x;
            s_kT[d0 + 1][row] = v.y;
            s_kT[d0 + 2][row] = v.z;
            s_kT[d0 + 3][row] = v.w;
        }
        __syncthreads();

        // ---- 4 rows x 1 col micro-tile GEMM
        float a[4] = {0.f, 0.f, 0.f, 0.f};
        #pragma unroll
        for (int d = 0; d < DD; d += 4) {
            const float4 q0 = *reinterpret_cast<const float4*>(&s_q[ty     ][d]);
            const float4 q1 = *reinterpret_cast<const float4*>(&s_q[ty +  4][d]);
            const float4 q2 = *reinterpret_cast<const float4*>(&s_q[ty +  8][d]);
            const float4 q3 = *reinterpret_cast<const float4*>(&s_q[ty + 12][d]);
            const float k0 = s_kT[d + 0][tx];
            const float k1 = s_kT[d + 1][tx];
            const float k2 = s_kT[d + 2][tx];
            const float k3 = s_kT[d + 3][tx];
            a[0] = fmaf(q0.x, k0, a[0]); a[0] = fmaf(q0.y, k1, a[0]);
            a[0] = fmaf(q0.z, k2, a[0]); a[0] = fmaf(q0.w, k3, a[0]);
            a[1] = fmaf(q1.x, k0, a[1]); a[1] = fmaf(q1.y, k1, a[1]);
            a[1] = fmaf(q1.z, k2, a[1]); a[1] = fmaf(q1.w, k3, a[1]);
            a[2] = fmaf(q2.x, k0, a[2]); a[2] = fmaf(q2.y, k1, a[2]);
            a[2] = fmaf(q2.z, k2, a[2]); a[2] = fmaf(q2.w, k3, a[2]);
            a[3] = fmaf(q3.x, k0, a[3]); a[3] = fmaf(q3.y, k1, a[3]);
            a[3] = fmaf(q3.z, k2, a[3]); a[3] = fmaf(q3.w, k3, a[3]);
        }

        // ---- mask + record + running max
        const int c = ck * TK;
        #pragma unroll
        for (int i = 0; i < 4; ++i) {
            const int m = mb[(size_t)(ty + 4 * i) * SKL + c];
            const float v = m ? a[i] : -INFINITY;
            sc[i][ck] = v;
            pmax[i]   = fmaxf(pmax[i], v);
        }
    }

    // ---- softmax per row (each row owned entirely by one wave)
    #pragma unroll
    for (int i = 0; i < 4; ++i) {
        float m = pmax[i];
        #pragma unroll
        for (int off = 32; off > 0; off >>= 1)
            m = fmaxf(m, __shfl_xor(m, off, 64));

        float sum = 0.f;
        #pragma unroll
        for (int ck = 0; ck < NCK; ++ck) {
            const float e = __expf(sc[i][ck] - m);
            sc[i][ck] = e;
            sum += e;
        }
        #pragma unroll
        for (int off = 32; off > 0; off >>= 1)
            sum += __shfl_xor(sum, off, 64);

        const float rinv = 1.0f / sum;
        float* ob = out + ((size_t)b * SQL + (size_t)(r0 + ty + 4 * i)) * SKL + tx;
        #pragma unroll
        for (int ck = 0; ck < NCK; ++ck)
            ob[ck * TK] = sc[i][ck] * rinv;
    }
}

extern "C" void kernel_launch(void* const* d_in, const int* in_sizes, int n_in,
                              void* d_out, int out_size, void* d_ws, size_t ws_size,
                              hipStream_t stream) {
    const float* q    = (const float*)d_in[0];
    const float* k    = (const float*)d_in[1];
    const int*   mask = (const int*)d_in[2];
    float*       out  = (float*)d_out;

    dim3 grid(SQL / TQ, BB);   // 128 x 32 = 4096 blocks
    sdpa_fwd<<<grid, dim3(256), 0, stream>>>(q, k, mask, out);
}